// Round 8
// baseline (201.264 us; speedup 1.0000x reference)
//
#include <hip/hip_runtime.h>

// Workspace layout (float offsets)
#define WS_M      0        // Mt[r*100+p] = M[p][r] where M = w_lin2 @ w_lin1, 10000 floats
#define WS_K      10000    // K[c][a][b][ci][u][v], 2646 floats
#define WS_BETA   12646    // beta[c][a][b], 18 floats
#define WS_W9     12664    // W9[c][ci][dy][dx], 486 floats
#define WS_BT     13150    // beta_tot[c] (interior combined bias), 2 floats
#define WS_UIT    (16384 + 1638400)      // uiL[bc][l][p128] bf16, 2,097,152 ushorts
#define WS_UFT    (16384 + 2*1638400)    // ufL[bc][l][p128] bf16

typedef short bf16x8 __attribute__((ext_vector_type(8)));
typedef float f32x4  __attribute__((ext_vector_type(4)));

__device__ inline ushort f2bf(float f) {   // round-to-nearest-even
    unsigned u = __float_as_uint(f);
    unsigned r = (u + 0x7fffu + ((u >> 16) & 1u)) >> 16;
    return (ushort)r;
}

// ---------------------------------------------------------------------------
// Prep. blocks 0..39: Mt. blocks 40..42: K (block 40 also Beta+Bt).
// blocks 43..44: W9 from raw weights.
__global__ __launch_bounds__(256) void k_prep(const float* __restrict__ wl1,
                                              const float* __restrict__ wl2,
                                              const float* __restrict__ wc1,
                                              const float* __restrict__ bc1,
                                              const float* __restrict__ wc2,
                                              const float* __restrict__ bc2,
                                              float* __restrict__ ws) {
    int blk = blockIdx.x;
    int t = threadIdx.x;
    if (blk < 40) {
        int idx = blk * 256 + t;
        if (idx < 10000) {
            int p = idx / 100, r = idx % 100;
            float s = 0.f;
            for (int q = 0; q < 200; ++q)
                s += wl2[p * 200 + q] * wl1[q * 100 + r];
            ws[WS_M + r * 100 + p] = s;
        }
        return;
    }
    __shared__ float swc1[9408];   // 64*3*49
    __shared__ float swc2[1152];   // 2*64*9
    __shared__ float sBeta[18];
    for (int i = t; i < 9408; i += 256) swc1[i] = wc1[i];
    for (int i = t; i < 1152; i += 256) swc2[i] = wc2[i];
    __syncthreads();
    if (blk < 43) {
        int base = (blk - 40) * 882;
        for (int ii = t; ii < 882; ii += 256) {
            int idx = base + ii;
            int v = idx % 7; int t1 = idx / 7;
            int u = t1 % 7;  int t2 = t1 / 7;
            int ci = t2 % 3; int t3 = t2 / 3;
            int b = t3 % 3;  int t4 = t3 / 3;
            int a = t4 % 3;  int c = t4 / 3;
            float s = 0.f;
            for (int c64 = 0; c64 < 64; ++c64)
                s += swc2[((c * 64 + c64) * 3 + a) * 3 + b] *
                     swc1[((c64 * 3 + ci) * 7 + u) * 7 + v];
            ws[WS_K + idx] = s;
        }
        if (blk == 40) {
            if (t < 18) {
                int b = t % 3; int a = (t / 3) % 3; int c = t / 9;
                float s = 0.f;
                for (int c64 = 0; c64 < 64; ++c64)
                    s += swc2[((c * 64 + c64) * 3 + a) * 3 + b] * bc1[c64];
                sBeta[t] = s; ws[WS_BETA + t] = s;
            }
            __syncthreads();
            if (t < 2) {
                float s = bc2[t];
                for (int j2 = 0; j2 < 9; ++j2) s += sBeta[t * 9 + j2];
                ws[WS_BT + t] = s;
            }
        }
    } else {
        int idx = (blk - 43) * 243 + t;
        if (t < 243) {
            int dx = idx % 9; int t1 = idx / 9;
            int dy = t1 % 9;  int t2 = t1 / 9;
            int ci = t2 % 3;  int c = t2 / 3;
            float s = 0.f;
            for (int a = 0; a < 3; ++a) {
                int u = dy - a; if (u < 0 || u > 6) continue;
                for (int b = 0; b < 3; ++b) {
                    int v = dx - b; if (v < 0 || v > 6) continue;
                    for (int c64 = 0; c64 < 64; ++c64)
                        s += swc2[((c * 64 + c64) * 3 + a) * 3 + b] *
                             swc1[((c64 * 3 + ci) * 7 + u) * 7 + v];
                }
            }
            ws[WS_W9 + idx] = s;   // layout c*243 + ci*81 + dy*9 + dx
        }
    }
}

// ---------------------------------------------------------------------------
// Fused conv + inline ring-fix + merged trans. 20x20 tile = 2x2 patches.
// Grid (16,16,8) = 2048 blocks; LDS 18.1 KB -> 8 blocks/CU -> the whole grid
// is co-resident in ONE generation (no straggler tail; R7's 25% occupancy
// was a 512-block second generation at 2/CU).
// phase 1: W9 conv (+ exact ring correction inline) -> sP[0]; fea -> sP[1]
// phase 2: merged trans: one Mt pass feeds acc_i and acc_f -> sOut (bf16)
// phase 3: coalesced writeout of uiL and ufL (256 B rows)
__global__ __launch_bounds__(256, 8) void k_fuse(const float* __restrict__ x,
                                                 const float* __restrict__ wfm,
                                                 const float* __restrict__ bfm,
                                                 const float* __restrict__ ws,
                                                 ushort* __restrict__ uiL,
                                                 ushort* __restrict__ ufL) {
    union alignas(16) SMemU {
        float  sx[3][28][36];         // 12096 B, live: stage..phase1
        ushort sOut[2][2][4][128];    //  4096 B, live: trans..writeout
    };
    __shared__ SMemU smu;
    __shared__ float sP[2][2][100][4];   // [mat][plane][r][li]; 16B rows (b128)
    const int bx = blockIdx.x, by = blockIdx.y, b = blockIdx.z;
    const int t = threadIdx.x;
    const float* Mt   = ws + WS_M;
    const float* Kw   = ws + WS_K;
    const float* Beta = ws + WS_BETA;
    const float* W9   = ws + WS_W9;
    const float* Bt   = ws + WS_BT;
    const int gh0 = by * 20, gw0 = bx * 20;
    bool edgeblk = (by == 0) | (by == 15) | (bx == 0) | (bx == 15);

    // ---- stage x halo. Interior blocks: unconditional float4 rows
    // (gw0-4 = 20bx-4 is 0 mod 4 -> aligned; 28 floats = 7x float4).
    if (!edgeblk) {
        for (int i = t; i < 588; i += 256) {         // 3*28*7
            int ci = i / 196; int rem = i - ci * 196;
            int rr = rem / 7, c4 = rem - rr * 7;
            float4 v = *(const float4*)&x[(b * 3 + ci) * 102400 +
                                          (gh0 - 4 + rr) * 320 + (gw0 - 4) + c4 * 4];
            *(float4*)&smu.sx[ci][rr][c4 * 4] = v;
        }
    } else {
        for (int idx = t; idx < 3 * 28 * 28; idx += 256) {
            int ci = idx / 784; int rem = idx - ci * 784;
            int rr = rem / 28, cc = rem - rr * 28;
            int gh = gh0 - 4 + rr, gw = gw0 - 4 + cc;
            float v = 0.f;
            if ((unsigned)gh < 320u && (unsigned)gw < 320u)
                v = x[(b * 3 + ci) * 102400 + gh * 320 + gw];
            smu.sx[ci][rr][cc] = v;
        }
    }
    __syncthreads();

    // ---- phase 1: composite 9x9 conv -> sP[0] (ring-corrected inline);
    //               fea 1x1 -> sP[1]
    const int lh = t / 10, lw0 = (t % 10) * 2;   // valid for t<200
    if (t < 200) {
        float acc0[2], acc1[2];
        float bt0 = Bt[0], bt1 = Bt[1];
        acc0[0] = bt0; acc0[1] = bt0; acc1[0] = bt1; acc1[1] = bt1;
        #pragma unroll
        for (int ci = 0; ci < 3; ++ci) {
            #pragma unroll
            for (int dy = 0; dy < 9; ++dy) {
                const float* xr = &smu.sx[ci][lh + dy][lw0];
                float2 y0 = *(const float2*)(xr);
                float2 y1 = *(const float2*)(xr + 2);
                float2 y2 = *(const float2*)(xr + 4);
                float2 y3 = *(const float2*)(xr + 6);
                float2 y4 = *(const float2*)(xr + 8);
                float xv[10] = {y0.x, y0.y, y1.x, y1.y, y2.x,
                                y2.y, y3.x, y3.y, y4.x, y4.y};
                #pragma unroll
                for (int dx = 0; dx < 9; ++dx) {
                    float w0t = W9[ci * 81 + dy * 9 + dx];
                    float w1t = W9[243 + ci * 81 + dy * 9 + dx];
                    acc0[0] += w0t * xv[dx];
                    acc0[1] += w0t * xv[dx + 1];
                    acc1[0] += w1t * xv[dx];
                    acc1[1] += w1t * xv[dx + 1];
                }
            }
        }
        // inline exact ring correction (edge blocks only; same FP order as
        // the old store-then-subtract: result = acc - c with c summed apart)
        if (edgeblk) {
            #pragma unroll
            for (int j = 0; j < 2; ++j) {
                int h = gh0 + lh, w = gw0 + lw0 + j;
                if (h == 0 || h == 319 || w == 0 || w == 319) {
                    float c0 = 0.f, c1 = 0.f;
                    for (int a = 0; a < 3; ++a) {
                        int hh = h + a - 1;
                        for (int bb = 0; bb < 3; ++bb) {
                            int wwp = w + bb - 1;
                            bool invalid = ((unsigned)hh >= 320u) |
                                           ((unsigned)wwp >= 320u);
                            if (invalid) {
                                c0 += Beta[a * 3 + bb];
                                c1 += Beta[9 + a * 3 + bb];
                                for (int ci = 0; ci < 3; ++ci) {
                                    const float* Kc = Kw + ((a * 3 + bb) * 3 + ci) * 49;
                                    #pragma unroll
                                    for (int u = 0; u < 7; ++u) {
                                        #pragma unroll
                                        for (int v = 0; v < 7; ++v) {
                                            float xv = smu.sx[ci][lh + a + u][lw0 + j + bb + v];
                                            c0 += Kc[u * 7 + v] * xv;
                                            c1 += Kc[1323 + u * 7 + v] * xv;
                                        }
                                    }
                                }
                            }
                        }
                    }
                    acc0[j] -= c0;
                    acc1[j] -= c1;
                }
            }
        }
        float wf00 = wfm[0], wf01 = wfm[1], wf02 = wfm[2];
        float wf10 = wfm[3], wf11 = wfm[4], wf12 = wfm[5];
        float bf0 = bfm[0], bf1 = bfm[1];
        #pragma unroll
        for (int j = 0; j < 2; ++j) {
            int lw = lw0 + j;
            int li = (lh / 10) * 2 + lw / 10;
            int r  = (lh % 10) * 10 + lw % 10;
            sP[0][0][r][li] = acc0[j];
            sP[0][1][r][li] = acc1[j];
            float s0 = smu.sx[0][4 + lh][4 + lw];
            float s1 = smu.sx[1][4 + lh][4 + lw];
            float s2 = smu.sx[2][4 + lh][4 + lw];
            sP[1][0][r][li] = (bf0 + s0 * wf00 + s1 * wf01 + s2 * wf02) * 0.25f;
            sP[1][1][r][li] = (bf1 + s0 * wf10 + s1 * wf11 + s2 * wf12) * 0.25f;
        }
    }
    __syncthreads();       // sx DEAD from here; sOut takes the union

    // ---- phase 2: merged trans. Lanes 0..199: (plane,p); ONE Mt pass feeds
    // both acc_i and acc_f. sP reads are wave-uniform b128 broadcasts
    // (conflict-free). Lanes 200..255: zero p-pad [100,128) in sOut.
    if (t < 200) {
        int plane = (t >= 100) ? 1 : 0;
        int p = t - plane * 100;
        float ai[4] = {0.f, 0.f, 0.f, 0.f};
        float af[4] = {0.f, 0.f, 0.f, 0.f};
        #pragma unroll 4
        for (int r = 0; r < 100; ++r) {
            float m = Mt[r * 100 + p];
            f32x4 si = *(const f32x4*)&sP[0][plane][r][0];
            f32x4 sf = *(const f32x4*)&sP[1][plane][r][0];
            #pragma unroll
            for (int k = 0; k < 4; ++k) {
                ai[k] += m * si[k];
                af[k] += m * sf[k];
            }
        }
        #pragma unroll
        for (int k = 0; k < 4; ++k) {
            smu.sOut[0][plane][k][p] = f2bf(fmaxf(ai[k], 0.f));
            smu.sOut[1][plane][k][p] = f2bf(fmaxf(af[k], 0.f));
        }
    } else {
        #pragma unroll
        for (int pass = 0; pass < 2; ++pass) {
            int task = (t - 200) + pass * 56;   // 112 tasks: mat,plane,k,q
            int mat = task / 56; int rem = task % 56;
            int plane = rem / 28; int rem2 = rem % 28;
            int k = rem2 / 7, q = rem2 % 7;
            *(uint2*)&smu.sOut[mat][plane][k][100 + q * 4] = make_uint2(0u, 0u);
        }
    }
    __syncthreads();

    // ---- phase 3: coalesced writeout, 256 thr = 2 mats x 8 rows x 16 lanes
    {
        int mat = t >> 7;
        int row = (t >> 4) & 7;
        int plane = row >> 2, k = row & 3;
        int lane16 = t & 15;
        int bc = b * 2 + plane;
        int l = (by * 2 + (k >> 1)) * 32 + bx * 2 + (k & 1);
        ushort* dst = mat ? ufL : uiL;
        uint4 v = *(const uint4*)&smu.sOut[mat][plane][k][lane16 * 8];
        *(uint4*)&dst[((size_t)bc * 1024 + l) * 128 + lane16 * 8] = v;
    }
}

// ---------------------------------------------------------------------------
// att[bc][l][m] = (1/100) * sum_p ui[l][p]*uf[m][p], bf16 MFMA 16x16x32.
// 64x128 tile/block, grid (8,16,16) = 2048 blocks (~8/CU for TLP).
// 4 waves 2x2; each wave 32x64 = 2x4 mfma tiles.
__global__ __launch_bounds__(256) void k_att(const ushort* __restrict__ ui,
                                             const ushort* __restrict__ uf,
                                             float* __restrict__ out) {
    int bc   = blockIdx.z;
    int row0 = blockIdx.y * 64, col0 = blockIdx.x * 128;
    int wave = threadIdx.x >> 6, lane = threadIdx.x & 63;
    int r0 = row0 + (wave >> 1) * 32;
    int c0 = col0 + (wave & 1) * 64;
    int m = lane & 15, quad = lane >> 4;
    const ushort* ub = ui + (size_t)bc * 1024 * 128;
    const ushort* vb = uf + (size_t)bc * 1024 * 128;
    f32x4 acc[2][4];
    #pragma unroll
    for (int i = 0; i < 2; ++i)
        #pragma unroll
        for (int j = 0; j < 4; ++j)
            acc[i][j] = (f32x4){0.f, 0.f, 0.f, 0.f};
    #pragma unroll
    for (int k0 = 0; k0 < 128; k0 += 32) {
        bf16x8 af[2], bfr[4];
        #pragma unroll
        for (int i = 0; i < 2; ++i)
            af[i] = *(const bf16x8*)&ub[(size_t)(r0 + i * 16 + m) * 128 + k0 + quad * 8];
        #pragma unroll
        for (int j = 0; j < 4; ++j)
            bfr[j] = *(const bf16x8*)&vb[(size_t)(c0 + j * 16 + m) * 128 + k0 + quad * 8];
        #pragma unroll
        for (int i = 0; i < 2; ++i)
            #pragma unroll
            for (int j = 0; j < 4; ++j)
                acc[i][j] = __builtin_amdgcn_mfma_f32_16x16x32_bf16(af[i], bfr[j], acc[i][j], 0, 0, 0);
    }
    // C/D: col = lane&15, row = quad*4 + reg (m89/m91-verified)
    #pragma unroll
    for (int i = 0; i < 2; ++i) {
        #pragma unroll
        for (int r = 0; r < 4; ++r) {
            int row = r0 + i * 16 + quad * 4 + r;
            float* o = out + ((size_t)bc * 1024 + row) * 1024;
            #pragma unroll
            for (int j = 0; j < 4; ++j)
                o[c0 + j * 16 + m] = acc[i][j][r] * 0.01f;
        }
    }
}

extern "C" void kernel_launch(void* const* d_in, const int* in_sizes, int n_in,
                              void* d_out, int out_size, void* d_ws, size_t ws_size,
                              hipStream_t stream) {
    const float* x       = (const float*)d_in[0];
    const float* w_conv1 = (const float*)d_in[1];
    const float* b_conv1 = (const float*)d_in[2];
    const float* w_conv2 = (const float*)d_in[3];
    const float* b_conv2 = (const float*)d_in[4];
    const float* w_fm    = (const float*)d_in[5];
    const float* b_fm    = (const float*)d_in[6];
    const float* w_lin1  = (const float*)d_in[7];
    const float* w_lin2  = (const float*)d_in[8];
    float* out = (float*)d_out;
    float* ws  = (float*)d_ws;
    ushort* uiL = (ushort*)(ws + WS_UIT);
    ushort* ufL = (ushort*)(ws + WS_UFT);

    k_prep<<<45, 256, 0, stream>>>(w_lin1, w_lin2, w_conv1, b_conv1, w_conv2, b_conv2, ws);
    k_fuse<<<dim3(16, 16, 8), 256, 0, stream>>>(x, w_fm, b_fm, ws, uiL, ufL);
    k_att<<<dim3(8, 16, 16), 256, 0, stream>>>(uiL, ufL, out);
}